// Round 1
// baseline (659.269 us; speedup 1.0000x reference)
//
#include <hip/hip_runtime.h>
#include <stdint.h>

typedef unsigned short u16;
typedef __attribute__((ext_vector_type(8))) short bf16x8;
typedef __attribute__((ext_vector_type(4))) float f32x4;

#define MFMA(a,b,c) __builtin_amdgcn_mfma_f32_16x16x32_bf16((a),(b),(c),0,0,0)

static constexpr int S  = 4096;
static constexpr int D  = 768;
static constexpr int H  = 12;
static constexpr int HD = 64;

// float -> bf16 round-nearest-even
__device__ __forceinline__ u16 f2b(float f){
  union { float f; unsigned u; } v; v.f = f;
  unsigned r = (v.u + 0x7fffu + ((v.u >> 16) & 1u)) >> 16;
  return (u16)r;
}

// ---------------- cast fp32 -> bf16, 4 elems/thread ----------------
__global__ void castk(const float* __restrict__ s, u16* __restrict__ d, int n4){
  int i = blockIdx.x * 256 + threadIdx.x;
  if (i >= n4) return;
  float4 v = ((const float4*)s)[i];
  uint2 o;
  o.x = (unsigned)f2b(v.x) | ((unsigned)f2b(v.y) << 16);
  o.y = (unsigned)f2b(v.z) | ((unsigned)f2b(v.w) << 16);
  ((uint2*)d)[i] = o;
}

// ---------------- QKV GEMM: [8192,768] x Wt[768,768] -> Q/K ([b][h][s][hd]) or Vt ([b][h][hd][s])
// 128x128 tile, 4 waves in 2x2, each wave 64x64 (4x4 MFMA tiles), BK=32.
__global__ __launch_bounds__(256, 2) void qkv_gemm(
    const u16* __restrict__ xb, const u16* __restrict__ wq, const u16* __restrict__ wk,
    const u16* __restrict__ wv, u16* __restrict__ Qb, u16* __restrict__ Kb, u16* __restrict__ Vt)
{
  __shared__ __align__(16) u16 As[128 * 40];  // stride 40 u16 = 80B, bank-conflict pad
  __shared__ __align__(16) u16 Bs[128 * 40];
  const int t = threadIdx.x;
  const int mblk = blockIdx.x, nblk = blockIdx.y, z = blockIdx.z;
  const u16* W = (z == 0) ? wq : (z == 1) ? wk : wv;
  const int w = t >> 6, lane = t & 63, quad = lane >> 4, l16 = lane & 15;
  const int wr = w >> 1, wc = w & 1;

  f32x4 acc[4][4];
  #pragma unroll
  for (int i = 0; i < 4; i++)
    #pragma unroll
    for (int j = 0; j < 4; j++) acc[i][j] = (f32x4){0.f, 0.f, 0.f, 0.f};

  const int row0 = t >> 2;          // 0..63
  const int kc   = (t & 3) * 8;     // 0,8,16,24
  const u16* gA = xb + (size_t)(mblk * 128 + row0) * D + kc;
  const u16* gB = W  + (size_t)(nblk * 128 + row0) * D + kc;

  for (int k0 = 0; k0 < D; k0 += 32) {
    bf16x8 va0 = *(const bf16x8*)(gA + k0);
    bf16x8 va1 = *(const bf16x8*)(gA + (size_t)64 * D + k0);
    bf16x8 vb0 = *(const bf16x8*)(gB + k0);
    bf16x8 vb1 = *(const bf16x8*)(gB + (size_t)64 * D + k0);
    __syncthreads();  // previous iter's LDS reads complete
    *(bf16x8*)(As + row0 * 40 + kc)        = va0;
    *(bf16x8*)(As + (row0 + 64) * 40 + kc) = va1;
    *(bf16x8*)(Bs + row0 * 40 + kc)        = vb0;
    *(bf16x8*)(Bs + (row0 + 64) * 40 + kc) = vb1;
    __syncthreads();
    bf16x8 af[4], bfr[4];
    #pragma unroll
    for (int mt = 0; mt < 4; mt++) af[mt]  = *(const bf16x8*)(As + (wr * 64 + mt * 16 + l16) * 40 + quad * 8);
    #pragma unroll
    for (int nt = 0; nt < 4; nt++) bfr[nt] = *(const bf16x8*)(Bs + (wc * 64 + nt * 16 + l16) * 40 + quad * 8);
    #pragma unroll
    for (int mt = 0; mt < 4; mt++)
      #pragma unroll
      for (int nt = 0; nt < 4; nt++)
        acc[mt][nt] = MFMA(af[mt], bfr[nt], acc[mt][nt]);
  }

  // epilogue: D-tile mapping col = lane&15 (n), row = quad*4+reg (m)
  #pragma unroll
  for (int mt = 0; mt < 4; mt++) {
    int m0 = mblk * 128 + wr * 64 + mt * 16 + quad * 4;   // +reg
    #pragma unroll
    for (int nt = 0; nt < 4; nt++) {
      int n = nblk * 128 + wc * 64 + nt * 16 + l16;
      int h = n >> 6, hd = n & 63;
      if (z == 2) {
        int b = m0 >> 12, s0 = m0 & 4095;
        u16* p = Vt + (((size_t)(b * H + h) * HD + hd)) * S + s0;  // 4 consecutive s
        uint2 pk;
        pk.x = (unsigned)f2b(acc[mt][nt][0]) | ((unsigned)f2b(acc[mt][nt][1]) << 16);
        pk.y = (unsigned)f2b(acc[mt][nt][2]) | ((unsigned)f2b(acc[mt][nt][3]) << 16);
        *(uint2*)p = pk;
      } else {
        u16* dst = (z == 0) ? Qb : Kb;
        #pragma unroll
        for (int r = 0; r < 4; r++) {
          int m = m0 + r; int b = m >> 12, s = m & 4095;
          dst[((size_t)(b * H + h) * S + s) * HD + hd] = f2b(acc[mt][nt][r]);
        }
      }
    }
  }
}

// ---------------- flash attention, causal. block = (128-query tile, b*h), 4 independent waves (32 rows each)
__global__ __launch_bounds__(256, 2) void attn(
    const u16* __restrict__ Qb, const u16* __restrict__ Kb,
    const u16* __restrict__ Vt, u16* __restrict__ ctx)
{
  __shared__ __align__(16) u16 Pb[4][32 * 136];  // per-wave P tile, stride 136 u16 (16B-aligned rows)
  const int t = threadIdx.x, w = t >> 6, lane = t & 63, quad = lane >> 4, l16 = lane & 15;
  const int qblk = blockIdx.x, bh = blockIdx.y;
  const int q0 = qblk * 128;
  const u16* Qh = Qb + (size_t)bh * S * HD;
  const u16* Kh = Kb + (size_t)bh * S * HD;
  const u16* Vh = Vt + (size_t)bh * S * HD;   // [64][4096]
  u16* Pw = &Pb[w][0];

  // Q fragments in registers: A-layout m=lane&15, k=quad*8+j
  bf16x8 aq[2][2];
  #pragma unroll
  for (int rt = 0; rt < 2; rt++)
    #pragma unroll
    for (int ks = 0; ks < 2; ks++)
      aq[rt][ks] = *(const bf16x8*)(Qh + (size_t)(q0 + w * 32 + rt * 16 + l16) * HD + ks * 32 + quad * 8);

  f32x4 ao[2][4];
  #pragma unroll
  for (int rt = 0; rt < 2; rt++)
    #pragma unroll
    for (int co = 0; co < 4; co++) ao[rt][co] = (f32x4){0.f, 0.f, 0.f, 0.f};
  float mrun[2][4], lrun[2][4];
  #pragma unroll
  for (int rt = 0; rt < 2; rt++)
    #pragma unroll
    for (int r = 0; r < 4; r++) { mrun[rt][r] = -1e30f; lrun[rt][r] = 0.f; }

  for (int kv0 = 0; kv0 <= q0; kv0 += 128) {
    const bool diag = (kv0 == q0);
    const int ct_end = diag ? (2 * w + 2) : 8;   // wave-uniform
    f32x4 sacc[2][8];
    #pragma unroll
    for (int rt = 0; rt < 2; rt++)
      #pragma unroll
      for (int ct = 0; ct < 8; ct++) sacc[rt][ct] = (f32x4){0.f, 0.f, 0.f, 0.f};

    // S = Q K^T
    #pragma unroll
    for (int ct = 0; ct < 8; ct++) {
      if (ct < ct_end) {
        bf16x8 bk0 = *(const bf16x8*)(Kh + (size_t)(kv0 + ct * 16 + l16) * HD +  0 + quad * 8);
        bf16x8 bk1 = *(const bf16x8*)(Kh + (size_t)(kv0 + ct * 16 + l16) * HD + 32 + quad * 8);
        #pragma unroll
        for (int rt = 0; rt < 2; rt++) {
          sacc[rt][ct] = MFMA(aq[rt][0], bk0, sacc[rt][ct]);
          sacc[rt][ct] = MFMA(aq[rt][1], bk1, sacc[rt][ct]);
        }
      }
    }

    // online softmax per row-tile
    #pragma unroll
    for (int rt = 0; rt < 2; rt++) {
      float tmax[4] = {-1e30f, -1e30f, -1e30f, -1e30f};
      #pragma unroll
      for (int ct = 0; ct < 8; ct++) {
        if (ct < ct_end) {
          #pragma unroll
          for (int r = 0; r < 4; r++) {
            float v = sacc[rt][ct][r] * 0.125f;   // 1/sqrt(64)
            if (diag) {
              int key = kv0 + ct * 16 + l16;
              int qr  = q0 + w * 32 + rt * 16 + quad * 4 + r;
              if (key > qr) v = -1e30f;
            }
            sacc[rt][ct][r] = v;
            tmax[r] = fmaxf(tmax[r], v);
          }
        }
      }
      #pragma unroll
      for (int r = 0; r < 4; r++) {
        float v = tmax[r];
        v = fmaxf(v, __shfl_xor(v, 1, 64));
        v = fmaxf(v, __shfl_xor(v, 2, 64));
        v = fmaxf(v, __shfl_xor(v, 4, 64));
        v = fmaxf(v, __shfl_xor(v, 8, 64));
        tmax[r] = v;
      }
      float alpha[4], tsum[4] = {0.f, 0.f, 0.f, 0.f};
      #pragma unroll
      for (int r = 0; r < 4; r++) {
        float mnew = fmaxf(mrun[rt][r], tmax[r]);
        alpha[r] = __expf(mrun[rt][r] - mnew);
        mrun[rt][r] = mnew;
      }
      #pragma unroll
      for (int ct = 0; ct < 8; ct++) {
        if (ct < ct_end) {
          #pragma unroll
          for (int r = 0; r < 4; r++) {
            float p = __expf(sacc[rt][ct][r] - mrun[rt][r]);
            tsum[r] += p;
            Pw[(rt * 16 + quad * 4 + r) * 136 + ct * 16 + l16] = f2b(p);
          }
        }
      }
      #pragma unroll
      for (int r = 0; r < 4; r++) {
        float v = tsum[r];
        v += __shfl_xor(v, 1, 64);
        v += __shfl_xor(v, 2, 64);
        v += __shfl_xor(v, 4, 64);
        v += __shfl_xor(v, 8, 64);
        lrun[rt][r] = lrun[rt][r] * alpha[r] + v;
      }
      #pragma unroll
      for (int co = 0; co < 4; co++)
        #pragma unroll
        for (int r = 0; r < 4; r++) ao[rt][co][r] *= alpha[r];
    }

    // O += P V   (P: A-layout from LDS; V: B-layout direct from Vt, contiguous along keys)
    const int ks_end = diag ? (w + 1) : 4;       // wave-uniform
    #pragma unroll
    for (int ks = 0; ks < 4; ks++) {
      if (ks < ks_end) {
        bf16x8 ap0 = *(const bf16x8*)(Pw + (0  + l16) * 136 + ks * 32 + quad * 8);
        bf16x8 ap1 = *(const bf16x8*)(Pw + (16 + l16) * 136 + ks * 32 + quad * 8);
        #pragma unroll
        for (int co = 0; co < 4; co++) {
          bf16x8 bv = *(const bf16x8*)(Vh + (size_t)(co * 16 + l16) * S + kv0 + ks * 32 + quad * 8);
          ao[0][co] = MFMA(ap0, bv, ao[0][co]);
          ao[1][co] = MFMA(ap1, bv, ao[1][co]);
        }
      }
    }
  }

  // normalize + store ctx as [token][h*64+hd] bf16
  const int b = bh / H, h = bh % H;
  #pragma unroll
  for (int rt = 0; rt < 2; rt++) {
    float inv[4];
    #pragma unroll
    for (int r = 0; r < 4; r++) inv[r] = 1.0f / lrun[rt][r];
    #pragma unroll
    for (int co = 0; co < 4; co++) {
      int col = h * HD + co * 16 + l16;
      #pragma unroll
      for (int r = 0; r < 4; r++) {
        int token = b * S + q0 + w * 32 + rt * 16 + quad * 4 + r;
        ctx[(size_t)token * D + col] = f2b(ao[rt][co][r] * inv[r]);
      }
    }
  }
}

// ---------------- output projection: ctx[8192,768] x Wo^T + bias -> fp32 out
__global__ __launch_bounds__(256, 2) void out_gemm(
    const u16* __restrict__ ctx, const u16* __restrict__ wo,
    const float* __restrict__ bias, float* __restrict__ out)
{
  __shared__ __align__(16) u16 As[128 * 40];
  __shared__ __align__(16) u16 Bs[128 * 40];
  const int t = threadIdx.x;
  const int mblk = blockIdx.x, nblk = blockIdx.y;
  const int w = t >> 6, lane = t & 63, quad = lane >> 4, l16 = lane & 15;
  const int wr = w >> 1, wc = w & 1;

  f32x4 acc[4][4];
  #pragma unroll
  for (int i = 0; i < 4; i++)
    #pragma unroll
    for (int j = 0; j < 4; j++) acc[i][j] = (f32x4){0.f, 0.f, 0.f, 0.f};

  const int row0 = t >> 2;
  const int kc   = (t & 3) * 8;
  const u16* gA = ctx + (size_t)(mblk * 128 + row0) * D + kc;
  const u16* gB = wo  + (size_t)(nblk * 128 + row0) * D + kc;

  for (int k0 = 0; k0 < D; k0 += 32) {
    bf16x8 va0 = *(const bf16x8*)(gA + k0);
    bf16x8 va1 = *(const bf16x8*)(gA + (size_t)64 * D + k0);
    bf16x8 vb0 = *(const bf16x8*)(gB + k0);
    bf16x8 vb1 = *(const bf16x8*)(gB + (size_t)64 * D + k0);
    __syncthreads();
    *(bf16x8*)(As + row0 * 40 + kc)        = va0;
    *(bf16x8*)(As + (row0 + 64) * 40 + kc) = va1;
    *(bf16x8*)(Bs + row0 * 40 + kc)        = vb0;
    *(bf16x8*)(Bs + (row0 + 64) * 40 + kc) = vb1;
    __syncthreads();
    bf16x8 af[4], bfr[4];
    #pragma unroll
    for (int mt = 0; mt < 4; mt++) af[mt]  = *(const bf16x8*)(As + (wr * 64 + mt * 16 + l16) * 40 + quad * 8);
    #pragma unroll
    for (int nt = 0; nt < 4; nt++) bfr[nt] = *(const bf16x8*)(Bs + (wc * 64 + nt * 16 + l16) * 40 + quad * 8);
    #pragma unroll
    for (int mt = 0; mt < 4; mt++)
      #pragma unroll
      for (int nt = 0; nt < 4; nt++)
        acc[mt][nt] = MFMA(af[mt], bfr[nt], acc[mt][nt]);
  }

  #pragma unroll
  for (int mt = 0; mt < 4; mt++) {
    int m0 = mblk * 128 + wr * 64 + mt * 16 + quad * 4;
    #pragma unroll
    for (int nt = 0; nt < 4; nt++) {
      int n = nblk * 128 + wc * 64 + nt * 16 + l16;
      float bv = bias[n];
      #pragma unroll
      for (int r = 0; r < 4; r++)
        out[(size_t)(m0 + r) * D + n] = acc[mt][nt][r] + bv;
    }
  }
}

// ---------------- host launch ----------------
extern "C" void kernel_launch(void* const* d_in, const int* in_sizes, int n_in,
                              void* d_out, int out_size, void* d_ws, size_t ws_size,
                              hipStream_t stream) {
  const float* x    = (const float*)d_in[0];
  const float* wq   = (const float*)d_in[1];
  const float* wk   = (const float*)d_in[2];
  const float* wv   = (const float*)d_in[3];
  const float* wo   = (const float*)d_in[4];
  const float* bo   = (const float*)d_in[5];
  float* out = (float*)d_out;

  u16* ws = (u16*)d_ws;
  const size_t NX = (size_t)2 * S * D;      // 6291456
  const size_t NW = (size_t)D * D;          // 589824
  u16* xb  = ws;                // [8192][768]; reused as ctx after qkv_gemm consumes it
  u16* wqb = ws + NX;
  u16* wkb = wqb + NW;
  u16* wvb = wkb + NW;
  u16* wob = wvb + NW;
  u16* Qb  = wob + NW;          // [2][12][4096][64]
  u16* Kb  = Qb + NX;
  u16* Vt  = Kb + NX;           // [2][12][64][4096]
  u16* ctx = xb;

  castk<<<(int)((NX / 4 + 255) / 256), 256, 0, stream>>>(x,  xb,  (int)(NX / 4));
  castk<<<(int)((NW / 4 + 255) / 256), 256, 0, stream>>>(wq, wqb, (int)(NW / 4));
  castk<<<(int)((NW / 4 + 255) / 256), 256, 0, stream>>>(wk, wkb, (int)(NW / 4));
  castk<<<(int)((NW / 4 + 255) / 256), 256, 0, stream>>>(wv, wvb, (int)(NW / 4));
  castk<<<(int)((NW / 4 + 255) / 256), 256, 0, stream>>>(wo, wob, (int)(NW / 4));

  qkv_gemm<<<dim3(64, 6, 3), 256, 0, stream>>>(xb, wqb, wkb, wvb, Qb, Kb, Vt);
  attn<<<dim3(S / 128, 2 * H), 256, 0, stream>>>(Qb, Kb, Vt, ctx);
  out_gemm<<<dim3(64, 6), 256, 0, stream>>>(ctx, wob, bo, out);
}

// Round 2
// 431.307 us; speedup vs baseline: 1.5285x; 1.5285x over previous
//
#include <hip/hip_runtime.h>
#include <stdint.h>

typedef unsigned short u16;
typedef __attribute__((ext_vector_type(8))) short bf16x8;
typedef __attribute__((ext_vector_type(4))) float f32x4;

#define MFMA(a,b,c) __builtin_amdgcn_mfma_f32_16x16x32_bf16((a),(b),(c),0,0,0)

static constexpr int S  = 4096;
static constexpr int D  = 768;
static constexpr int H  = 12;
static constexpr int HD = 64;

// float -> bf16 round-nearest-even
__device__ __forceinline__ u16 f2b(float f){
  union { float f; unsigned u; } v; v.f = f;
  unsigned r = (v.u + 0x7fffu + ((v.u >> 16) & 1u)) >> 16;
  return (u16)r;
}

// ---------------- cast fp32 -> bf16, 4 elems/thread ----------------
__global__ void castk(const float* __restrict__ s, u16* __restrict__ d, int n4){
  int i = blockIdx.x * 256 + threadIdx.x;
  if (i >= n4) return;
  float4 v = ((const float4*)s)[i];
  uint2 o;
  o.x = (unsigned)f2b(v.x) | ((unsigned)f2b(v.y) << 16);
  o.y = (unsigned)f2b(v.z) | ((unsigned)f2b(v.w) << 16);
  ((uint2*)d)[i] = o;
}

// ---------------- QKV GEMM: [8192,768] x Wt[768,768] -> Q/K ([b][h][s][hd]) or Vt ([b][h][hd][s])
__global__ __launch_bounds__(256, 2) void qkv_gemm(
    const u16* __restrict__ xb, const u16* __restrict__ wq, const u16* __restrict__ wk,
    const u16* __restrict__ wv, u16* __restrict__ Qb, u16* __restrict__ Kb, u16* __restrict__ Vt)
{
  __shared__ __align__(16) u16 As[128 * 40];
  __shared__ __align__(16) u16 Bs[128 * 40];
  const int t = threadIdx.x;
  const int mblk = blockIdx.x, nblk = blockIdx.y, z = blockIdx.z;
  const u16* W = (z == 0) ? wq : (z == 1) ? wk : wv;
  const int w = t >> 6, lane = t & 63, quad = lane >> 4, l16 = lane & 15;
  const int wr = w >> 1, wc = w & 1;

  f32x4 acc[4][4];
  #pragma unroll
  for (int i = 0; i < 4; i++)
    #pragma unroll
    for (int j = 0; j < 4; j++) acc[i][j] = (f32x4){0.f, 0.f, 0.f, 0.f};

  const int row0 = t >> 2;
  const int kc   = (t & 3) * 8;
  const u16* gA = xb + (size_t)(mblk * 128 + row0) * D + kc;
  const u16* gB = W  + (size_t)(nblk * 128 + row0) * D + kc;

  for (int k0 = 0; k0 < D; k0 += 32) {
    bf16x8 va0 = *(const bf16x8*)(gA + k0);
    bf16x8 va1 = *(const bf16x8*)(gA + (size_t)64 * D + k0);
    bf16x8 vb0 = *(const bf16x8*)(gB + k0);
    bf16x8 vb1 = *(const bf16x8*)(gB + (size_t)64 * D + k0);
    __syncthreads();
    *(bf16x8*)(As + row0 * 40 + kc)        = va0;
    *(bf16x8*)(As + (row0 + 64) * 40 + kc) = va1;
    *(bf16x8*)(Bs + row0 * 40 + kc)        = vb0;
    *(bf16x8*)(Bs + (row0 + 64) * 40 + kc) = vb1;
    __syncthreads();
    bf16x8 af[4], bfr[4];
    #pragma unroll
    for (int mt = 0; mt < 4; mt++) af[mt]  = *(const bf16x8*)(As + (wr * 64 + mt * 16 + l16) * 40 + quad * 8);
    #pragma unroll
    for (int nt = 0; nt < 4; nt++) bfr[nt] = *(const bf16x8*)(Bs + (wc * 64 + nt * 16 + l16) * 40 + quad * 8);
    #pragma unroll
    for (int mt = 0; mt < 4; mt++)
      #pragma unroll
      for (int nt = 0; nt < 4; nt++)
        acc[mt][nt] = MFMA(af[mt], bfr[nt], acc[mt][nt]);
  }

  #pragma unroll
  for (int mt = 0; mt < 4; mt++) {
    int m0 = mblk * 128 + wr * 64 + mt * 16 + quad * 4;
    #pragma unroll
    for (int nt = 0; nt < 4; nt++) {
      int n = nblk * 128 + wc * 64 + nt * 16 + l16;
      int h = n >> 6, hd = n & 63;
      if (z == 2) {
        int b = m0 >> 12, s0 = m0 & 4095;
        u16* p = Vt + (((size_t)(b * H + h) * HD + hd)) * S + s0;
        uint2 pk;
        pk.x = (unsigned)f2b(acc[mt][nt][0]) | ((unsigned)f2b(acc[mt][nt][1]) << 16);
        pk.y = (unsigned)f2b(acc[mt][nt][2]) | ((unsigned)f2b(acc[mt][nt][3]) << 16);
        *(uint2*)p = pk;
      } else {
        u16* dst = (z == 0) ? Qb : Kb;
        #pragma unroll
        for (int r = 0; r < 4; r++) {
          int m = m0 + r; int b = m >> 12, s = m & 4095;
          dst[((size_t)(b * H + h) * S + s) * HD + hd] = f2b(acc[mt][nt][r]);
        }
      }
    }
  }
}

// ---------------- flash attention (transposed compute: S^T = K Q^T, O^T = V^T P^T) ----------------
// block = (qblk pair (pr, 31-pr), b*h); 4 independent waves, each owns 32 query rows.
__global__ __launch_bounds__(256, 3) void attn(
    const u16* __restrict__ Qb, const u16* __restrict__ Kb,
    const u16* __restrict__ Vt, u16* __restrict__ ctx)
{
  __shared__ __align__(16) u16 Pb[4][32 * 136];  // per-wave P tile: row=query(32), col=key(128), stride 136
  const int t = threadIdx.x, w = t >> 6, lane = t & 63, quad = lane >> 4, l16 = lane & 15;
  const int pr = blockIdx.x, bh = blockIdx.y;
  const u16* Qh = Qb + (size_t)bh * S * HD;
  const u16* Kh = Kb + (size_t)bh * S * HD;
  const u16* Vh = Vt + (size_t)bh * S * HD;   // [64][4096]
  u16* Pw = &Pb[w][0];
  const int b = bh / H, h = bh % H;

  for (int half = 0; half < 2; half++) {
    const int qblk = (half == 0) ? pr : (31 - pr);
    const int q0 = qblk * 128;

    // Q fragments (B-operand layout): lane holds Q[query=l16+rt*16+w*32+q0][hd=ks*32+quad*8+j]
    bf16x8 qf[2][2];
    #pragma unroll
    for (int rt = 0; rt < 2; rt++)
      #pragma unroll
      for (int ks = 0; ks < 2; ks++)
        qf[rt][ks] = *(const bf16x8*)(Qh + (size_t)(q0 + w * 32 + rt * 16 + l16) * HD + ks * 32 + quad * 8);

    f32x4 ao[2][4];                 // O^T acc: row=hd (co*16+quad*4+r), col=query (rt*16+l16)
    #pragma unroll
    for (int rt = 0; rt < 2; rt++)
      #pragma unroll
      for (int co = 0; co < 4; co++) ao[rt][co] = (f32x4){0.f, 0.f, 0.f, 0.f};
    float mrun[2] = {-1e30f, -1e30f};
    float lrun[2] = {0.f, 0.f};

    for (int kv0 = 0; kv0 <= q0; kv0 += 128) {
      const bool diag = (kv0 == q0);
      const int ct_end = diag ? (2 * w + 2) : 8;   // wave-uniform
      f32x4 sacc[2][8];
      #pragma unroll
      for (int rt = 0; rt < 2; rt++)
        #pragma unroll
        for (int ct = 0; ct < 8; ct++) sacc[rt][ct] = (f32x4){0.f, 0.f, 0.f, 0.f};

      // S^T = K Q^T : row=key (ct*16+quad*4+r), col=query (l16)
      #pragma unroll
      for (int ct = 0; ct < 8; ct++) {
        if (ct < ct_end) {
          bf16x8 kf0 = *(const bf16x8*)(Kh + (size_t)(kv0 + ct * 16 + l16) * HD +  0 + quad * 8);
          bf16x8 kf1 = *(const bf16x8*)(Kh + (size_t)(kv0 + ct * 16 + l16) * HD + 32 + quad * 8);
          #pragma unroll
          for (int rt = 0; rt < 2; rt++) {
            sacc[rt][ct] = MFMA(kf0, qf[rt][0], sacc[rt][ct]);
            sacc[rt][ct] = MFMA(kf1, qf[rt][1], sacc[rt][ct]);
          }
        }
      }

      // online softmax: per lane, 4 keys/tile for query l16; reduce in-register then across quads
      #pragma unroll
      for (int rt = 0; rt < 2; rt++) {
        float tm = -1e30f;
        #pragma unroll
        for (int ct = 0; ct < 8; ct++) {
          if (ct < ct_end) {
            #pragma unroll
            for (int r = 0; r < 4; r++) {
              float v = sacc[rt][ct][r] * 0.125f;   // 1/sqrt(64)
              if (diag) {
                int key = kv0 + ct * 16 + quad * 4 + r;
                int qr  = q0 + w * 32 + rt * 16 + l16;
                if (key > qr) v = -1e30f;
              }
              sacc[rt][ct][r] = v;
              tm = fmaxf(tm, v);
            }
          }
        }
        tm = fmaxf(tm, __shfl_xor(tm, 16, 64));
        tm = fmaxf(tm, __shfl_xor(tm, 32, 64));
        float mnew = fmaxf(mrun[rt], tm);
        float alpha = __expf(mrun[rt] - mnew);
        mrun[rt] = mnew;
        float ts = 0.f;
        #pragma unroll
        for (int ct = 0; ct < 8; ct++) {
          if (ct < ct_end) {
            float p0 = __expf(sacc[rt][ct][0] - mnew);
            float p1 = __expf(sacc[rt][ct][1] - mnew);
            float p2 = __expf(sacc[rt][ct][2] - mnew);
            float p3 = __expf(sacc[rt][ct][3] - mnew);
            ts += (p0 + p1) + (p2 + p3);
            uint2 pk;
            pk.x = (unsigned)f2b(p0) | ((unsigned)f2b(p1) << 16);
            pk.y = (unsigned)f2b(p2) | ((unsigned)f2b(p3) << 16);
            *(uint2*)(Pw + (rt * 16 + l16) * 136 + ct * 16 + quad * 4) = pk;   // 4 consecutive keys
          }
        }
        ts += __shfl_xor(ts, 16, 64);
        ts += __shfl_xor(ts, 32, 64);
        lrun[rt] = lrun[rt] * alpha + ts;
        #pragma unroll
        for (int co = 0; co < 4; co++)
          #pragma unroll
          for (int r = 0; r < 4; r++) ao[rt][co][r] *= alpha;
      }

      // O^T += V^T P^T  (A = V^T frag from Vt; B = P^T frag from per-wave LDS — no barrier needed)
      const int ks_end = diag ? (w + 1) : 4;       // wave-uniform
      #pragma unroll
      for (int ks = 0; ks < 4; ks++) {
        if (ks < ks_end) {
          bf16x8 pf0 = *(const bf16x8*)(Pw + (0  + l16) * 136 + ks * 32 + quad * 8);
          bf16x8 pf1 = *(const bf16x8*)(Pw + (16 + l16) * 136 + ks * 32 + quad * 8);
          #pragma unroll
          for (int co = 0; co < 4; co++) {
            bf16x8 vf = *(const bf16x8*)(Vh + (size_t)(co * 16 + l16) * S + kv0 + ks * 32 + quad * 8);
            ao[0][co] = MFMA(vf, pf0, ao[0][co]);
            ao[1][co] = MFMA(vf, pf1, ao[1][co]);
          }
        }
      }
    }

    // epilogue: lane holds hd = co*16+quad*4+{0..3} (consecutive) for query rt*16+l16 -> packed 8B store
    #pragma unroll
    for (int rt = 0; rt < 2; rt++) {
      float inv = 1.0f / lrun[rt];
      int token = b * S + q0 + w * 32 + rt * 16 + l16;
      #pragma unroll
      for (int co = 0; co < 4; co++) {
        uint2 pk;
        pk.x = (unsigned)f2b(ao[rt][co][0] * inv) | ((unsigned)f2b(ao[rt][co][1] * inv) << 16);
        pk.y = (unsigned)f2b(ao[rt][co][2] * inv) | ((unsigned)f2b(ao[rt][co][3] * inv) << 16);
        *(uint2*)(ctx + (size_t)token * D + h * HD + co * 16 + quad * 4) = pk;
      }
    }
  }
}

// ---------------- output projection: ctx[8192,768] x Wo^T + bias -> fp32 out
__global__ __launch_bounds__(256, 2) void out_gemm(
    const u16* __restrict__ ctx, const u16* __restrict__ wo,
    const float* __restrict__ bias, float* __restrict__ out)
{
  __shared__ __align__(16) u16 As[128 * 40];
  __shared__ __align__(16) u16 Bs[128 * 40];
  const int t = threadIdx.x;
  const int mblk = blockIdx.x, nblk = blockIdx.y;
  const int w = t >> 6, lane = t & 63, quad = lane >> 4, l16 = lane & 15;
  const int wr = w >> 1, wc = w & 1;

  f32x4 acc[4][4];
  #pragma unroll
  for (int i = 0; i < 4; i++)
    #pragma unroll
    for (int j = 0; j < 4; j++) acc[i][j] = (f32x4){0.f, 0.f, 0.f, 0.f};

  const int row0 = t >> 2;
  const int kc   = (t & 3) * 8;
  const u16* gA = ctx + (size_t)(mblk * 128 + row0) * D + kc;
  const u16* gB = wo  + (size_t)(nblk * 128 + row0) * D + kc;

  for (int k0 = 0; k0 < D; k0 += 32) {
    bf16x8 va0 = *(const bf16x8*)(gA + k0);
    bf16x8 va1 = *(const bf16x8*)(gA + (size_t)64 * D + k0);
    bf16x8 vb0 = *(const bf16x8*)(gB + k0);
    bf16x8 vb1 = *(const bf16x8*)(gB + (size_t)64 * D + k0);
    __syncthreads();
    *(bf16x8*)(As + row0 * 40 + kc)        = va0;
    *(bf16x8*)(As + (row0 + 64) * 40 + kc) = va1;
    *(bf16x8*)(Bs + row0 * 40 + kc)        = vb0;
    *(bf16x8*)(Bs + (row0 + 64) * 40 + kc) = vb1;
    __syncthreads();
    bf16x8 af[4], bfr[4];
    #pragma unroll
    for (int mt = 0; mt < 4; mt++) af[mt]  = *(const bf16x8*)(As + (wr * 64 + mt * 16 + l16) * 40 + quad * 8);
    #pragma unroll
    for (int nt = 0; nt < 4; nt++) bfr[nt] = *(const bf16x8*)(Bs + (wc * 64 + nt * 16 + l16) * 40 + quad * 8);
    #pragma unroll
    for (int mt = 0; mt < 4; mt++)
      #pragma unroll
      for (int nt = 0; nt < 4; nt++)
        acc[mt][nt] = MFMA(af[mt], bfr[nt], acc[mt][nt]);
  }

  #pragma unroll
  for (int mt = 0; mt < 4; mt++) {
    int m0 = mblk * 128 + wr * 64 + mt * 16 + quad * 4;
    #pragma unroll
    for (int nt = 0; nt < 4; nt++) {
      int n = nblk * 128 + wc * 64 + nt * 16 + l16;
      float bv = bias[n];
      #pragma unroll
      for (int r = 0; r < 4; r++)
        out[(size_t)(m0 + r) * D + n] = acc[mt][nt][r] + bv;
    }
  }
}

// ---------------- host launch ----------------
extern "C" void kernel_launch(void* const* d_in, const int* in_sizes, int n_in,
                              void* d_out, int out_size, void* d_ws, size_t ws_size,
                              hipStream_t stream) {
  const float* x    = (const float*)d_in[0];
  const float* wq   = (const float*)d_in[1];
  const float* wk   = (const float*)d_in[2];
  const float* wv   = (const float*)d_in[3];
  const float* wo   = (const float*)d_in[4];
  const float* bo   = (const float*)d_in[5];
  float* out = (float*)d_out;

  u16* ws = (u16*)d_ws;
  const size_t NX = (size_t)2 * S * D;      // 6291456
  const size_t NW = (size_t)D * D;          // 589824
  u16* xb  = ws;                // [8192][768]; reused as ctx after qkv_gemm consumes it
  u16* wqb = ws + NX;
  u16* wkb = wqb + NW;
  u16* wvb = wkb + NW;
  u16* wob = wvb + NW;
  u16* Qb  = wob + NW;          // [2][12][4096][64]
  u16* Kb  = Qb + NX;
  u16* Vt  = Kb + NX;           // [2][12][64][4096]
  u16* ctx = xb;

  castk<<<(int)((NX / 4 + 255) / 256), 256, 0, stream>>>(x,  xb,  (int)(NX / 4));
  castk<<<(int)((NW / 4 + 255) / 256), 256, 0, stream>>>(wq, wqb, (int)(NW / 4));
  castk<<<(int)((NW / 4 + 255) / 256), 256, 0, stream>>>(wk, wkb, (int)(NW / 4));
  castk<<<(int)((NW / 4 + 255) / 256), 256, 0, stream>>>(wv, wvb, (int)(NW / 4));
  castk<<<(int)((NW / 4 + 255) / 256), 256, 0, stream>>>(wo, wob, (int)(NW / 4));

  qkv_gemm<<<dim3(64, 6, 3), 256, 0, stream>>>(xb, wqb, wkb, wvb, Qb, Kb, Vt);
  attn<<<dim3(16, 2 * H), 256, 0, stream>>>(Qb, Kb, Vt, ctx);
  out_gemm<<<dim3(64, 6), 256, 0, stream>>>(ctx, wob, bo, out);
}